// Round 1
// baseline (117.005 us; speedup 1.0000x reference)
//
#include <hip/hip_runtime.h>
#include <hip/hip_bf16.h>
#include <stdint.h>
#include <stddef.h>

// NT-Xent loss, B=4096, D=256, N=8192, T=0.5.
// Pipeline: normalize -> fused ZZ^T GEMM + exp row-sum (flash-style, no NxN
// materialization) -> per-row loss -> mean reduce.

#define B_ROWS 4096
#define D_DIM  256
#define N_ROWS 8192
#define BM 128
#define BN 128
#define BK 64

typedef __bf16 bf16;
typedef bf16  bf16x8  __attribute__((ext_vector_type(8)));
typedef bf16  bf16x4  __attribute__((ext_vector_type(4)));
typedef float floatx4 __attribute__((ext_vector_type(4)));

// ---------------------------------------------------------------- normalize
// One wave per row: 256 fp32 -> L2-normalized bf16.
__global__ __launch_bounds__(256) void normalize_kernel(
    const float* __restrict__ z_i, const float* __restrict__ z_j,
    bf16* __restrict__ zn) {
  const int wave = threadIdx.x >> 6;
  const int lane = threadIdx.x & 63;
  const int row  = blockIdx.x * 4 + wave;
  const float* src = (row < B_ROWS) ? (z_i + (size_t)row * D_DIM)
                                    : (z_j + (size_t)(row - B_ROWS) * D_DIM);
  float4 v = ((const float4*)src)[lane];
  float ss = v.x * v.x + v.y * v.y + v.z * v.z + v.w * v.w;
  #pragma unroll
  for (int m = 1; m < 64; m <<= 1) ss += __shfl_xor(ss, m);
  const float rn = rsqrtf(ss);
  bf16x4 o;
  o[0] = (bf16)(v.x * rn);
  o[1] = (bf16)(v.y * rn);
  o[2] = (bf16)(v.z * rn);
  o[3] = (bf16)(v.w * rn);
  ((bf16x4*)(zn + (size_t)row * D_DIM))[lane] = o;
}

// ------------------------------------------------------- fused sim+exp+sum
// Grid: 64 row-tiles x 8 col-chunks = 512 blocks; each block does 8 j-tiles
// of 128 cols. m97 structure: 128x128 tile, 4 waves (2x2), each wave 4x4
// frags of 16x16x32 bf16 MFMA, BK=64 single-buffer LDS staged via
// global_load_lds width=16. Epilogue per j-tile: e=exp(2*sim) (diag->0),
// accumulate per-row, one atomicAdd per row per wave at the end.
__global__ __launch_bounds__(256, 2) void simexp_kernel(
    const bf16* __restrict__ zn, float* __restrict__ sumexp) {
  __shared__ __align__(16) bf16 As[BM * BK];
  __shared__ __align__(16) bf16 Bs[BN * BK];

  const int tid   = threadIdx.x;
  const int wave  = tid >> 6;
  const int lane  = tid & 63;
  const int lcol  = lane & 15;   // MFMA: A row / B col / C col
  const int lquad = lane >> 4;   // MFMA: k-group / C row-group
  const int wr = (wave >> 1) * 64;  // wave row offset in 128-tile
  const int wc = (wave & 1) * 64;   // wave col offset
  const int ri = blockIdx.x >> 3;   // row tile 0..63
  const int ci = blockIdx.x & 7;    // col chunk 0..7
  const int row_base = ri * BM;

  float rowsum[4][4];  // [ti][reg] ; row = wr + ti*16 + lquad*4 + reg
  #pragma unroll
  for (int ti = 0; ti < 4; ++ti)
    #pragma unroll
    for (int r = 0; r < 4; ++r) rowsum[ti][r] = 0.f;

  for (int t = 0; t < 8; ++t) {
    const int jt = ci * 8 + t;
    const int col_base = jt * BN;

    floatx4 acc[4][4];
    #pragma unroll
    for (int ti = 0; ti < 4; ++ti)
      #pragma unroll
      for (int tj = 0; tj < 4; ++tj) acc[ti][tj] = floatx4{0.f, 0.f, 0.f, 0.f};

    for (int kb = 0; kb < D_DIM / BK; ++kb) {
      __syncthreads();  // previous tile's LDS reads done before overwrite
      #pragma unroll
      for (int it = 0; it < 4; ++it) {
        const int chunk = it * 256 + tid;      // 0..1023, lane-contiguous
        const int m  = chunk >> 3;             // 0..127
        const int kk = (chunk & 7) << 3;       // 0,8,..,56
        const bf16* ga = zn + (size_t)(row_base + m) * D_DIM + kb * BK + kk;
        const bf16* gb = zn + (size_t)(col_base + m) * D_DIM + kb * BK + kk;
        __builtin_amdgcn_global_load_lds(
            (const __attribute__((address_space(1))) unsigned int*)ga,
            (__attribute__((address_space(3))) unsigned int*)&As[chunk * 8],
            16, 0, 0);
        __builtin_amdgcn_global_load_lds(
            (const __attribute__((address_space(1))) unsigned int*)gb,
            (__attribute__((address_space(3))) unsigned int*)&Bs[chunk * 8],
            16, 0, 0);
      }
      __syncthreads();  // implies vmcnt(0): staging visible

      #pragma unroll
      for (int ks = 0; ks < BK; ks += 32) {
        bf16x8 af[4], bfr[4];
        #pragma unroll
        for (int ti = 0; ti < 4; ++ti)
          af[ti] = *(const bf16x8*)&As[(wr + ti * 16 + lcol) * BK + ks + lquad * 8];
        #pragma unroll
        for (int tj = 0; tj < 4; ++tj)
          bfr[tj] = *(const bf16x8*)&Bs[(wc + tj * 16 + lcol) * BK + ks + lquad * 8];
        #pragma unroll
        for (int ti = 0; ti < 4; ++ti)
          #pragma unroll
          for (int tj = 0; tj < 4; ++tj)
            acc[ti][tj] = __builtin_amdgcn_mfma_f32_16x16x32_bf16(
                af[ti], bfr[tj], acc[ti][tj], 0, 0, 0);
      }
    }

    // epilogue: e = exp(sim/T) = exp(2*dot); diagonal masked to 0
    const bool diag = (ri == jt);
    #pragma unroll
    for (int ti = 0; ti < 4; ++ti) {
      #pragma unroll
      for (int tj = 0; tj < 4; ++tj) {
        #pragma unroll
        for (int r = 0; r < 4; ++r) {
          const float v = acc[ti][tj][r];
          float e = __expf(2.0f * v);
          if (diag) {
            const int rrow = wr + ti * 16 + lquad * 4 + r;
            const int rcol = wc + tj * 16 + lcol;
            if (rrow == rcol) e = 0.f;
          }
          rowsum[ti][r] += e;
        }
      }
    }
  }

  // reduce the 16 col-lanes (bits 0..3 of lane), then 1 atomic per row/wave
  #pragma unroll
  for (int ti = 0; ti < 4; ++ti) {
    #pragma unroll
    for (int r = 0; r < 4; ++r) {
      float s = rowsum[ti][r];
      s += __shfl_xor(s, 1);
      s += __shfl_xor(s, 2);
      s += __shfl_xor(s, 4);
      s += __shfl_xor(s, 8);
      if (lcol == 0) {
        const int grow = row_base + wr + ti * 16 + lquad * 4 + r;
        atomicAdd(&sumexp[grow], s);
      }
    }
  }
}

// ------------------------------------------------------------- per-row loss
// One wave per row: loss_i = log(sumexp_i) - 2*dot(zn_i, zn_partner)
__global__ __launch_bounds__(256) void finalize_kernel(
    const bf16* __restrict__ zn, const float* __restrict__ sumexp,
    float* __restrict__ loss) {
  const int wave = threadIdx.x >> 6;
  const int lane = threadIdx.x & 63;
  const int row  = blockIdx.x * 4 + wave;
  const int partner = (row < B_ROWS) ? row + B_ROWS : row - B_ROWS;
  bf16x4 av = ((const bf16x4*)(zn + (size_t)row * D_DIM))[lane];
  bf16x4 bv = ((const bf16x4*)(zn + (size_t)partner * D_DIM))[lane];
  float d = 0.f;
  #pragma unroll
  for (int j = 0; j < 4; ++j) d += (float)av[j] * (float)bv[j];
  #pragma unroll
  for (int m = 1; m < 64; m <<= 1) d += __shfl_xor(d, m);
  if (lane == 0) loss[row] = __logf(sumexp[row]) - 2.0f * d;
}

// ----------------------------------------------------------------- mean
__global__ __launch_bounds__(1024) void reduce_kernel(
    const float* __restrict__ loss, float* __restrict__ out) {
  __shared__ float ws[16];
  const int tid = threadIdx.x;
  float s = 0.f;
  for (int k = tid; k < N_ROWS; k += 1024) s += loss[k];
  #pragma unroll
  for (int m = 1; m < 64; m <<= 1) s += __shfl_xor(s, m);
  const int wave = tid >> 6, lane = tid & 63;
  if (lane == 0) ws[wave] = s;
  __syncthreads();
  if (wave == 0) {
    float t = (lane < 16) ? ws[lane] : 0.f;
    #pragma unroll
    for (int m = 1; m < 16; m <<= 1) t += __shfl_xor(t, m);
    if (lane == 0) out[0] = t * (1.0f / N_ROWS);
  }
}

extern "C" void kernel_launch(void* const* d_in, const int* in_sizes, int n_in,
                              void* d_out, int out_size, void* d_ws,
                              size_t ws_size, hipStream_t stream) {
  const float* z_i = (const float*)d_in[0];
  const float* z_j = (const float*)d_in[1];
  float* out = (float*)d_out;

  // workspace layout: zn (4 MB bf16) | sumexp (32 KB) | loss (32 KB)
  bf16* zn = (bf16*)d_ws;
  float* sumexp = (float*)((char*)d_ws + (size_t)N_ROWS * D_DIM * sizeof(bf16));
  float* loss = sumexp + N_ROWS;

  hipMemsetAsync(sumexp, 0, N_ROWS * sizeof(float), stream);
  normalize_kernel<<<N_ROWS / 4, 256, 0, stream>>>(z_i, z_j, zn);
  simexp_kernel<<<(N_ROWS / BM) * 8, 256, 0, stream>>>(zn, sumexp);
  finalize_kernel<<<N_ROWS / 4, 256, 0, stream>>>(zn, sumexp, loss);
  reduce_kernel<<<1, 1024, 0, stream>>>(loss, out);
}